// Round 2
// baseline (1103.369 us; speedup 1.0000x reference)
//
#include <hip/hip_runtime.h>

#define NN 100000
#define EE 1600000
#define DTc 0.1f
#define REGc 1e-6f
#define WQc (1.0f / 64.0f)

#define SCAN_BS 512
#define SCAN_NB ((NN + SCAN_BS - 1) / SCAN_BS)   // 196

// ---------------------------------------------------------------------------
// Histogram: deg_out[src]++ (for q_e) and cnt[n]++ for BOTH endpoints
// (combined incidence degree).
// ---------------------------------------------------------------------------
__global__ __launch_bounds__(256) void hist_kernel(const int* __restrict__ esrc,
                                                   const int* __restrict__ edst,
                                                   int* __restrict__ deg_out,
                                                   int* __restrict__ cnt) {
    int i = blockIdx.x * 256 + threadIdx.x;
    if (i < EE) {
        int s = esrc[i], d = edst[i];
        atomicAdd(&deg_out[s], 1);
        atomicAdd(&cnt[s], 1);
        atomicAdd(&cnt[d], 1);
    }
}

// ---------------------------------------------------------------------------
// 3-kernel exclusive scan of cnt[NN] -> offs
// ---------------------------------------------------------------------------
__global__ __launch_bounds__(SCAN_BS) void scan_blocks(const int* __restrict__ cnt,
                                                       int* __restrict__ offs,
                                                       int* __restrict__ bsums) {
    __shared__ int s[SCAN_BS];
    int t = threadIdx.x;
    int i = blockIdx.x * SCAN_BS + t;
    int v = (i < NN) ? cnt[i] : 0;
    s[t] = v;
    __syncthreads();
    for (int o = 1; o < SCAN_BS; o <<= 1) {
        int x = (t >= o) ? s[t - o] : 0;
        __syncthreads();
        s[t] += x;
        __syncthreads();
    }
    offs[i] = s[t] - v;                      // exclusive within block
    if (t == 0) bsums[blockIdx.x] = s[SCAN_BS - 1];
}

__global__ __launch_bounds__(256) void scan_sums(int* __restrict__ bsums) {
    __shared__ int s[256];
    int t = threadIdx.x;
    int v = (t < SCAN_NB) ? bsums[t] : 0;
    s[t] = v;
    __syncthreads();
    for (int o = 1; o < 256; o <<= 1) {
        int x = (t >= o) ? s[t - o] : 0;
        __syncthreads();
        s[t] += x;
        __syncthreads();
    }
    if (t < SCAN_NB) bsums[t] = s[t] - v;    // exclusive
}

__global__ __launch_bounds__(SCAN_BS) void add_offsets(int* __restrict__ offs,
                                                       const int* __restrict__ bsums,
                                                       int* __restrict__ cursor) {
    int i = blockIdx.x * SCAN_BS + threadIdx.x;
    int o = offs[i] + bsums[blockIdx.x];
    offs[i] = o;
    if (i < NN) cursor[i] = o;
}

// ---------------------------------------------------------------------------
// Scatter edges into combined incidence CSR: for edge (s->d) with
// q = ew/deg_out[s], append (d, q) to s's list and (s, q) to d's list.
// ---------------------------------------------------------------------------
__global__ __launch_bounds__(256) void scatter_kernel(
    const int* __restrict__ esrc, const int* __restrict__ edst,
    const float* __restrict__ ew, const int* __restrict__ deg_out,
    int* __restrict__ cursor, int* __restrict__ adj_other,
    float* __restrict__ adj_q) {
    int i = blockIdx.x * 256 + threadIdx.x;
    if (i < EE) {
        int s = esrc[i], d = edst[i];
        float q = ew[i] / (float)deg_out[s];
        int p1 = atomicAdd(&cursor[s], 1);
        adj_other[p1] = d;
        adj_q[p1] = q;
        int p2 = atomicAdd(&cursor[d], 1);
        adj_other[p2] = s;
        adj_q[p2] = q;
    }
}

// ---------------------------------------------------------------------------
// Gather transport: one wave per node, lane = velocity bin.
// trans[n] = xi * (sum_j q_j * f+[other_j]  -  (sum_j q_j) * f+[n])
// ---------------------------------------------------------------------------
__global__ __launch_bounds__(256) void gather_kernel(
    const float* __restrict__ f, const int* __restrict__ offs,
    const int* __restrict__ cnt, const int* __restrict__ adj_other,
    const float* __restrict__ adj_q, const float* __restrict__ xi,
    float* __restrict__ trans) {
    int lane = threadIdx.x & 63;
    int n = blockIdx.x * 4 + (threadIdx.x >> 6);
    if (n >= NN) return;
    int start = offs[n];
    int num = cnt[n];
    float acc = 0.f, qs = 0.f;
    for (int j = 0; j < num; j++) {
        int o = adj_other[start + j];
        float q = adj_q[start + j];
        acc = fmaf(q, fmaxf(f[o * 64 + lane], 0.f), acc);
        qs += q;
    }
    float fn = fmaxf(f[n * 64 + lane], 0.f);
    trans[n * 64 + lane] = xi[lane] * (acc - qs * fn);
}

// ---------------------------------------------------------------------------
// Per-node: clamp f -> 5-layer MLP (relu x4, tanh) -> collision-invariance
// projection (analytic 2x2) -> fused final update with transport+source+relu.
// ---------------------------------------------------------------------------
__global__ __launch_bounds__(128) void node_kernel(
    const float* __restrict__ f, const float* __restrict__ macro_u,
    const float* __restrict__ source, const float* __restrict__ xi,
    const float* __restrict__ w_in, const float* __restrict__ b_in,
    const float* __restrict__ w_hid, const float* __restrict__ b_hid,
    const float* __restrict__ w_out, const float* __restrict__ b_out,
    const float* __restrict__ trans, float* __restrict__ out) {
    __shared__ float sbuf[128 * 65];
    __shared__ float s0s[128], s1s[128], us[128];

    const int t = threadIdx.x;
    const int nodeBase = blockIdx.x * 128;
    const int gbase = nodeBase * 64;
    const int total = NN * 64;

    for (int i = 0; i < 64; i++) {
        int l = i * 128 + t;
        int g = gbase + l;
        float v = 0.f;
        if (g < total) v = fmaxf(f[g], 0.f);
        sbuf[(l >> 6) * 65 + (l & 63)] = v;
    }
    __syncthreads();

    const int n = nodeBase + t;
    const bool valid = (n < NN);
    const float u = valid ? macro_u[n] : 0.f;

    float* myrow = &sbuf[t * 65];
    float x[64];
#pragma unroll
    for (int q = 0; q < 64; q++) x[q] = myrow[q];

    float v0 = 0.f, v1 = 0.f, sxs = 0.f, sxs2 = 0.f;

    for (int layer = 0; layer < 5; layer++) {
        const float* W;
        const float* B;
        if (layer == 0)      { W = w_in;                        B = b_in; }
        else if (layer < 4)  { W = w_hid + (layer - 1) * 4096;  B = b_hid + (layer - 1) * 64; }
        else                 { W = w_out;                       B = b_out; }
        const bool last = (layer == 4);

        for (int h = 0; h < 64; h += 8) {
            float a[8];
#pragma unroll
            for (int j = 0; j < 8; j++) a[j] = B[h + j];
#pragma unroll
            for (int q = 0; q < 64; q++) {
                float xv = x[q];
                const float* wr = W + q * 64 + h;
#pragma unroll
                for (int j = 0; j < 8; j++) a[j] = fmaf(xv, wr[j], a[j]);
            }
            if (!last) {
#pragma unroll
                for (int j = 0; j < 8; j++) myrow[h + j] = fmaxf(a[j], 0.f);
            } else {
#pragma unroll
                for (int j = 0; j < 8; j++) {
                    float om = tanhf(a[j]);
                    float xs = xi[h + j] + u;
                    v0 += WQc * om;
                    v1 += WQc * xs * om;
                    sxs += xs;
                    sxs2 += xs * xs;
                    myrow[h + j] = om;
                }
            }
        }
        if (layer < 4) {
#pragma unroll
            for (int q = 0; q < 64; q++) x[q] = myrow[q];
        }
    }

    float c00 = WQc + REGc;
    float c01 = WQc * WQc * sxs;
    float c11 = WQc * WQc * sxs2 + REGc;
    float det = c00 * c11 - c01 * c01;
    float inv = 1.0f / det;
    float sv0 = (c11 * v0 - c01 * v1) * inv;
    float sv1 = (c00 * v1 - c01 * v0) * inv;
    s0s[t] = sv0;
    s1s[t] = sv1;
    us[t] = u;
    __syncthreads();

    const float xiq = xi[t & 63];
    for (int i = 0; i < 64; i++) {
        int l = i * 128 + t;
        int g = gbase + l;
        if (g < total) {
            int nl = l >> 6;
            float om = sbuf[nl * 65 + (l & 63)];
            float xs = xiq + us[nl];
            float omst = om - WQc * (s0s[nl] + xs * s1s[nl]);
            float val = fmaxf(f[g], 0.f) + DTc * (source[g] + omst - trans[g]);
            out[g] = fmaxf(val, 0.f);
        }
    }
}

extern "C" void kernel_launch(void* const* d_in, const int* in_sizes, int n_in,
                              void* d_out, int out_size, void* d_ws, size_t ws_size,
                              hipStream_t stream) {
    const float* f       = (const float*)d_in[0];
    const float* macro_u = (const float*)d_in[1];
    const float* source  = (const float*)d_in[2];
    const int*   esrc    = (const int*)d_in[3];
    const int*   edst    = (const int*)d_in[4];
    const float* ew      = (const float*)d_in[5];
    const float* xi      = (const float*)d_in[6];
    const float* w_in    = (const float*)d_in[7];
    const float* b_in    = (const float*)d_in[8];
    const float* w_hid   = (const float*)d_in[9];
    const float* b_hid   = (const float*)d_in[10];
    const float* w_out   = (const float*)d_in[11];
    const float* b_out   = (const float*)d_in[12];
    float* out = (float*)d_out;

    // workspace layout (all 4-byte elements)
    int*   deg_out   = (int*)d_ws;                       // NN
    int*   cnt       = deg_out + NN;                     // NN
    int*   offs      = cnt + NN;                         // SCAN_NB*SCAN_BS
    int*   cursor    = offs + SCAN_NB * SCAN_BS;         // NN
    int*   bsums     = cursor + NN;                      // 256
    int*   adj_other = bsums + 256;                      // 2*EE
    float* adj_q     = (float*)(adj_other + 2 * EE);     // 2*EE
    float* trans     = adj_q + 2 * EE;                   // NN*64

    // zero only the histograms
    hipMemsetAsync(d_ws, 0, (size_t)(2 * NN) * sizeof(int), stream);

    hist_kernel<<<(EE + 255) / 256, 256, 0, stream>>>(esrc, edst, deg_out, cnt);
    scan_blocks<<<SCAN_NB, SCAN_BS, 0, stream>>>(cnt, offs, bsums);
    scan_sums<<<1, 256, 0, stream>>>(bsums);
    add_offsets<<<SCAN_NB, SCAN_BS, 0, stream>>>(offs, bsums, cursor);
    scatter_kernel<<<(EE + 255) / 256, 256, 0, stream>>>(esrc, edst, ew, deg_out,
                                                         cursor, adj_other, adj_q);
    gather_kernel<<<(NN + 3) / 4, 256, 0, stream>>>(f, offs, cnt, adj_other,
                                                    adj_q, xi, trans);
    node_kernel<<<(NN + 127) / 128, 128, 0, stream>>>(
        f, macro_u, source, xi, w_in, b_in, w_hid, b_hid, w_out, b_out, trans, out);
}

// Round 3
// 833.881 us; speedup vs baseline: 1.3232x; 1.3232x over previous
//
#include <hip/hip_runtime.h>

#define NN 100000
#define EE 1600000
#define DTc 0.1f
#define REGc 1e-6f
#define WQc (1.0f / 64.0f)

#define SCAN_BS 512
#define SCAN_NB ((NN + SCAN_BS - 1) / SCAN_BS)   // 196
#define ACT_S 72                                  // padded LDS row stride (bf16)

typedef __attribute__((ext_vector_type(8))) short short8;
typedef __attribute__((ext_vector_type(4))) float f32x4;

__device__ __forceinline__ short f2bf(float x) {
    unsigned u = __float_as_uint(x);
    unsigned r = (u + 0x7fffu + ((u >> 16) & 1u)) >> 16;   // RNE
    return (short)r;
}
__device__ __forceinline__ float bf2f(short s) {
    return __uint_as_float(((unsigned)(unsigned short)s) << 16);
}

// ---------------------------------------------------------------------------
// f+ = relu(f) as bf16 (gather + MLP input feed)
// ---------------------------------------------------------------------------
__global__ __launch_bounds__(256) void pre_kernel(const float* __restrict__ f,
                                                  unsigned short* __restrict__ fb16) {
    int i = blockIdx.x * 256 + threadIdx.x;
    if (i < NN * 64) fb16[i] = (unsigned short)f2bf(fmaxf(f[i], 0.f));
}

// ---------------------------------------------------------------------------
// Packed histogram: pk[n] = (out_deg << 32) | incidence_cnt
// ---------------------------------------------------------------------------
__global__ __launch_bounds__(256) void hist_kernel(const int* __restrict__ esrc,
                                                   const int* __restrict__ edst,
                                                   unsigned long long* __restrict__ pk) {
    int i = blockIdx.x * 256 + threadIdx.x;
    if (i < EE) {
        atomicAdd(&pk[esrc[i]], 0x100000001ULL);
        atomicAdd(&pk[edst[i]], 1ULL);
    }
}

// ---------------------------------------------------------------------------
// 3-kernel exclusive scan of lo32(pk) -> offs
// ---------------------------------------------------------------------------
__global__ __launch_bounds__(SCAN_BS) void scan_blocks(const unsigned long long* __restrict__ pk,
                                                       int* __restrict__ offs,
                                                       int* __restrict__ bsums) {
    __shared__ int s[SCAN_BS];
    int t = threadIdx.x;
    int i = blockIdx.x * SCAN_BS + t;
    int v = (i < NN) ? (int)(unsigned)pk[i] : 0;
    s[t] = v;
    __syncthreads();
    for (int o = 1; o < SCAN_BS; o <<= 1) {
        int x = (t >= o) ? s[t - o] : 0;
        __syncthreads();
        s[t] += x;
        __syncthreads();
    }
    offs[i] = s[t] - v;
    if (t == 0) bsums[blockIdx.x] = s[SCAN_BS - 1];
}

__global__ __launch_bounds__(256) void scan_sums(int* __restrict__ bsums) {
    __shared__ int s[256];
    int t = threadIdx.x;
    int v = (t < SCAN_NB) ? bsums[t] : 0;
    s[t] = v;
    __syncthreads();
    for (int o = 1; o < 256; o <<= 1) {
        int x = (t >= o) ? s[t - o] : 0;
        __syncthreads();
        s[t] += x;
        __syncthreads();
    }
    if (t < SCAN_NB) bsums[t] = s[t] - v;
}

__global__ __launch_bounds__(SCAN_BS) void add_offsets(int* __restrict__ offs,
                                                       const int* __restrict__ bsums,
                                                       int* __restrict__ cursor) {
    int i = blockIdx.x * SCAN_BS + threadIdx.x;
    int o = offs[i] + bsums[blockIdx.x];
    offs[i] = o;
    if (i < NN) cursor[i] = o;
}

// ---------------------------------------------------------------------------
// Scatter into combined incidence CSR; ONE 8-byte store per entry:
// adj[p] = (float_bits(q) << 32) | other_node
// ---------------------------------------------------------------------------
__global__ __launch_bounds__(256) void scatter_kernel(
    const int* __restrict__ esrc, const int* __restrict__ edst,
    const float* __restrict__ ew, const unsigned long long* __restrict__ pk,
    int* __restrict__ cursor, unsigned long long* __restrict__ adj) {
    int i = blockIdx.x * 256 + threadIdx.x;
    if (i < EE) {
        int s = esrc[i], d = edst[i];
        int deg = (int)(pk[s] >> 32);
        float q = ew[i] / (float)deg;
        unsigned long long qb = ((unsigned long long)__float_as_uint(q)) << 32;
        int p1 = atomicAdd(&cursor[s], 1);
        adj[p1] = qb | (unsigned)d;
        int p2 = atomicAdd(&cursor[d], 1);
        adj[p2] = qb | (unsigned)s;
    }
}

// ---------------------------------------------------------------------------
// Gather transport: one wave per node, lane = velocity bin (bf16 f rows).
// ---------------------------------------------------------------------------
__global__ __launch_bounds__(256) void gather_kernel(
    const unsigned short* __restrict__ fb16, const int* __restrict__ offs,
    const unsigned long long* __restrict__ adj, const float* __restrict__ xi,
    float* __restrict__ trans) {
    int lane = threadIdx.x & 63;
    int n = blockIdx.x * 4 + (threadIdx.x >> 6);
    if (n >= NN) return;
    int start = offs[n];
    int end = offs[n + 1];
    float acc = 0.f, qs = 0.f;
    for (int j = start; j < end; j++) {
        unsigned long long v = adj[j];
        int o = (int)(unsigned)v;
        float q = __uint_as_float((unsigned)(v >> 32));
        acc = fmaf(q, bf2f((short)fb16[o * 64 + lane]), acc);
        qs += q;
    }
    float fn = bf2f((short)fb16[n * 64 + lane]);
    trans[n * 64 + lane] = xi[lane] * (acc - qs * fn);
}

// ---------------------------------------------------------------------------
// MFMA node kernel: 256 thr / 4 waves / 128 nodes per block.
// Wave w owns act rows [32w, 32w+32) -> act hazards are wave-local; only the
// shared weight buffer needs barriers (2 per layer).
// mfma_f32_16x16x32_bf16: A[m=lane&15][k=quad*8+j], B[n=lane&15][k=quad*8+j],
// C/D col=lane&15, row=quad*4+reg  (doc-verified layouts).
// ---------------------------------------------------------------------------
__global__ __launch_bounds__(256) void node_kernel(
    const unsigned short* __restrict__ fb16, const float* __restrict__ f,
    const float* __restrict__ macro_u, const float* __restrict__ source,
    const float* __restrict__ xi,
    const float* __restrict__ w_in, const float* __restrict__ b_in,
    const float* __restrict__ w_hid, const float* __restrict__ b_hid,
    const float* __restrict__ w_out, const float* __restrict__ b_out,
    const float* __restrict__ trans, float* __restrict__ out) {
    __shared__ __attribute__((aligned(16))) short act[128 * ACT_S];   // 18.4 KB
    __shared__ __attribute__((aligned(16))) short wbuf[64 * ACT_S];   //  9.2 KB
    __shared__ float biasl[64];
    __shared__ float s0s[128], s1s[128], us[128], xif[64];

    const int t = threadIdx.x;
    const int wid = t >> 6;
    const int lane = t & 63;
    const int m = lane & 15;
    const int quad = lane >> 4;
    const int nodeBase = blockIdx.x * 128;
    const int gbase = nodeBase * 64;
    const int total = NN * 64;

    // per-node u, xi copy
    if (t < 128) {
        int n = nodeBase + t;
        us[t] = (n < NN) ? macro_u[n] : 0.f;
    }
    if (t < 64) xif[t] = xi[t];

    // stage clamped-bf16 f tile into act
    for (int i = 0; i < 32; i++) {
        int idx = i * 256 + t;
        int g = gbase + idx;
        short v = (g < total) ? (short)fb16[g] : (short)0;
        act[(idx >> 6) * ACT_S + (idx & 63)] = v;
    }

    const int rowbase = wid * 32;

    for (int l = 0; l < 5; l++) {
        const float* W = (l == 0) ? w_in : (l < 4 ? w_hid + (l - 1) * 4096 : w_out);
        const float* B = (l == 0) ? b_in : (l < 4 ? b_hid + (l - 1) * 64 : b_out);

        __syncthreads();   // prev-layer B-frag reads done; act writes visible
        // stage W^T (bf16) + bias
#pragma unroll
        for (int i = 0; i < 16; i++) {
            int idx = i * 256 + t;          // idx = k*64 + n
            int k = idx >> 6, n = idx & 63;
            wbuf[n * ACT_S + k] = f2bf(W[idx]);
        }
        if (t < 64) biasl[t] = B[t];
        __syncthreads();   // wbuf ready

        short8 Af[2][2], Bf[4][2];
#pragma unroll
        for (int rt = 0; rt < 2; rt++)
#pragma unroll
            for (int kk = 0; kk < 2; kk++)
                Af[rt][kk] = *(const short8*)&act[(rowbase + rt * 16 + m) * ACT_S + kk * 32 + quad * 8];
#pragma unroll
        for (int ct = 0; ct < 4; ct++)
#pragma unroll
            for (int kk = 0; kk < 2; kk++)
                Bf[ct][kk] = *(const short8*)&wbuf[(ct * 16 + m) * ACT_S + kk * 32 + quad * 8];

        f32x4 acc[2][4];
#pragma unroll
        for (int rt = 0; rt < 2; rt++)
#pragma unroll
            for (int ct = 0; ct < 4; ct++) {
                acc[rt][ct] = (f32x4){0.f, 0.f, 0.f, 0.f};
                acc[rt][ct] = __builtin_amdgcn_mfma_f32_16x16x32_bf16(Af[rt][0], Bf[ct][0], acc[rt][ct], 0, 0, 0);
                acc[rt][ct] = __builtin_amdgcn_mfma_f32_16x16x32_bf16(Af[rt][1], Bf[ct][1], acc[rt][ct], 0, 0, 0);
            }

        // epilogue: bias + relu/tanh, write back (wave-local rows only)
#pragma unroll
        for (int rt = 0; rt < 2; rt++)
#pragma unroll
            for (int ct = 0; ct < 4; ct++) {
                float bv = biasl[ct * 16 + m];
#pragma unroll
                for (int r = 0; r < 4; r++) {
                    int row = rowbase + rt * 16 + quad * 4 + r;
                    float val = acc[rt][ct][r] + bv;
                    val = (l < 4) ? fmaxf(val, 0.f) : tanhf(val);
                    act[row * ACT_S + ct * 16 + m] = f2bf(val);
                }
            }
    }
    __syncthreads();   // omega (bf16) visible to all

    // projection: analytic 2x2 Cramer per node
    if (t < 128) {
        int n = nodeBase + t;
        float u = us[t];
        float v0 = 0.f, v1 = 0.f, sxs2 = 0.f;
        const short* myrow = &act[t * ACT_S];
#pragma unroll
        for (int q = 0; q < 64; q++) {
            float om = bf2f(myrow[q]);
            float xs = xif[q] + u;
            v0 += om;
            v1 += xs * om;
            sxs2 += xs * xs;
        }
        v0 *= WQc;
        v1 *= WQc;
        float c00 = WQc + REGc;
        float c01 = WQc * WQc * (64.f * u);          // sum(xi)=0 (symmetric linspace)... kept exact below
        // exact: sum(xs) = sum(xi) + 64u ; compute sum(xi) once from xif
        float sxi = 0.f;
#pragma unroll
        for (int q = 0; q < 64; q++) sxi += xif[q];
        c01 = WQc * WQc * (sxi + 64.f * u);
        float c11 = WQc * WQc * sxs2 + REGc;
        float det = c00 * c11 - c01 * c01;
        float inv = 1.0f / det;
        s0s[t] = (c11 * v0 - c01 * v1) * inv;
        s1s[t] = (c00 * v1 - c01 * v0) * inv;
        (void)n;
    }
    __syncthreads();

    // fused output sweep
    const float xiq = xif[t & 63];
    for (int i = 0; i < 32; i++) {
        int idx = i * 256 + t;
        int g = gbase + idx;
        if (g < total) {
            int nl = idx >> 6;
            float om = bf2f(act[nl * ACT_S + (idx & 63)]);
            float xs = xiq + us[nl];
            float omst = om - WQc * (s0s[nl] + xs * s1s[nl]);
            float val = fmaxf(f[g], 0.f) + DTc * (source[g] + omst - trans[g]);
            out[g] = fmaxf(val, 0.f);
        }
    }
}

extern "C" void kernel_launch(void* const* d_in, const int* in_sizes, int n_in,
                              void* d_out, int out_size, void* d_ws, size_t ws_size,
                              hipStream_t stream) {
    const float* f       = (const float*)d_in[0];
    const float* macro_u = (const float*)d_in[1];
    const float* source  = (const float*)d_in[2];
    const int*   esrc    = (const int*)d_in[3];
    const int*   edst    = (const int*)d_in[4];
    const float* ew      = (const float*)d_in[5];
    const float* xi      = (const float*)d_in[6];
    const float* w_in    = (const float*)d_in[7];
    const float* b_in    = (const float*)d_in[8];
    const float* w_hid   = (const float*)d_in[9];
    const float* b_hid   = (const float*)d_in[10];
    const float* w_out   = (const float*)d_in[11];
    const float* b_out   = (const float*)d_in[12];
    float* out = (float*)d_out;

    // workspace layout (8-byte entries first)
    unsigned long long* pk  = (unsigned long long*)d_ws;     // NN
    unsigned long long* adj = pk + NN;                       // 2*EE
    int*   offs   = (int*)(adj + 2 * EE);                    // SCAN_NB*SCAN_BS
    int*   cursor = offs + SCAN_NB * SCAN_BS;                // NN
    int*   bsums  = cursor + NN;                             // 256
    float* trans  = (float*)(bsums + 256);                   // NN*64
    unsigned short* fb16 = (unsigned short*)(trans + (size_t)NN * 64);  // NN*64

    hipMemsetAsync(pk, 0, (size_t)NN * sizeof(unsigned long long), stream);

    pre_kernel<<<(NN * 64 + 255) / 256, 256, 0, stream>>>(f, fb16);
    hist_kernel<<<(EE + 255) / 256, 256, 0, stream>>>(esrc, edst, pk);
    scan_blocks<<<SCAN_NB, SCAN_BS, 0, stream>>>(pk, offs, bsums);
    scan_sums<<<1, 256, 0, stream>>>(bsums);
    add_offsets<<<SCAN_NB, SCAN_BS, 0, stream>>>(offs, bsums, cursor);
    scatter_kernel<<<(EE + 255) / 256, 256, 0, stream>>>(esrc, edst, ew, pk, cursor, adj);
    gather_kernel<<<(NN + 3) / 4, 256, 0, stream>>>(fb16, offs, adj, xi, trans);
    node_kernel<<<(NN + 127) / 128, 128 * 2, 0, stream>>>(
        fb16, f, macro_u, source, xi, w_in, b_in, w_hid, b_hid, w_out, b_out, trans, out);
}

// Round 5
// 571.962 us; speedup vs baseline: 1.9291x; 1.4579x over previous
//
#include <hip/hip_runtime.h>

#define NN 100000
#define EE 1600000
#define DTc 0.1f
#define REGc 1e-6f
#define WQc (1.0f / 64.0f)

#define SCAN_BS 512
#define SCAN_NB ((NN + SCAN_BS - 1) / SCAN_BS)   // 196
#define ACT_S 72                                  // padded LDS row stride (bf16)

typedef __attribute__((ext_vector_type(8))) short short8;
typedef __attribute__((ext_vector_type(4))) float f32x4;

__device__ __forceinline__ unsigned short f2bf(float x) {
    unsigned u = __float_as_uint(x);
    unsigned r = (u + 0x7fffu + ((u >> 16) & 1u)) >> 16;   // RNE
    return (unsigned short)r;
}
__device__ __forceinline__ float bf2f(unsigned short s) {
    return __uint_as_float(((unsigned)s) << 16);
}

// ---------------------------------------------------------------------------
// f+ = relu(f) as bf16, 4 elems/thread.  NN*64 floats -> NN*16 threads.
// ---------------------------------------------------------------------------
__global__ __launch_bounds__(256) void pre_kernel(const float* __restrict__ f,
                                                  unsigned int* __restrict__ fb16u) {
    int i = blockIdx.x * 256 + threadIdx.x;     // one float4 / two uints per thread
    if (i < NN * 16) {
        float4 v = *(const float4*)&f[i * 4];
        unsigned lo = (unsigned)f2bf(fmaxf(v.x, 0.f)) | ((unsigned)f2bf(fmaxf(v.y, 0.f)) << 16);
        unsigned hi = (unsigned)f2bf(fmaxf(v.z, 0.f)) | ((unsigned)f2bf(fmaxf(v.w, 0.f)) << 16);
        fb16u[i * 2] = lo;
        fb16u[i * 2 + 1] = hi;
    }
}

// ---------------------------------------------------------------------------
// Weight prep: wp[l][n*64+k] = bf16(W_l[k*64+n])  (transposed, B-frag ready)
// ---------------------------------------------------------------------------
__global__ __launch_bounds__(256) void wprep_kernel(
    const float* __restrict__ w_in, const float* __restrict__ w_hid,
    const float* __restrict__ w_out, unsigned short* __restrict__ wp) {
    int i = blockIdx.x * 256 + threadIdx.x;
    if (i < 5 * 4096) {
        int l = i >> 12, idx = i & 4095;
        int n = idx >> 6, k = idx & 63;
        const float* W = (l == 0) ? w_in : (l < 4 ? w_hid + (l - 1) * 4096 : w_out);
        wp[i] = f2bf(W[k * 64 + n]);
    }
}

// ---------------------------------------------------------------------------
// Packed histogram: pk[n] = (out_deg << 32) | incidence_cnt
// ---------------------------------------------------------------------------
__global__ __launch_bounds__(256) void hist_kernel(const int* __restrict__ esrc,
                                                   const int* __restrict__ edst,
                                                   unsigned long long* __restrict__ pk) {
    int i = blockIdx.x * 256 + threadIdx.x;
    if (i < EE) {
        atomicAdd(&pk[esrc[i]], 0x100000001ULL);
        atomicAdd(&pk[edst[i]], 1ULL);
    }
}

// ---------------------------------------------------------------------------
// 3-kernel exclusive scan of lo32(pk) -> offs
// ---------------------------------------------------------------------------
__global__ __launch_bounds__(SCAN_BS) void scan_blocks(const unsigned long long* __restrict__ pk,
                                                       int* __restrict__ offs,
                                                       int* __restrict__ bsums) {
    __shared__ int s[SCAN_BS];
    int t = threadIdx.x;
    int i = blockIdx.x * SCAN_BS + t;
    int v = (i < NN) ? (int)(unsigned)pk[i] : 0;
    s[t] = v;
    __syncthreads();
    for (int o = 1; o < SCAN_BS; o <<= 1) {
        int x = (t >= o) ? s[t - o] : 0;
        __syncthreads();
        s[t] += x;
        __syncthreads();
    }
    offs[i] = s[t] - v;
    if (t == 0) bsums[blockIdx.x] = s[SCAN_BS - 1];
}

__global__ __launch_bounds__(256) void scan_sums(int* __restrict__ bsums) {
    __shared__ int s[256];
    int t = threadIdx.x;
    int v = (t < SCAN_NB) ? bsums[t] : 0;
    s[t] = v;
    __syncthreads();
    for (int o = 1; o < 256; o <<= 1) {
        int x = (t >= o) ? s[t - o] : 0;
        __syncthreads();
        s[t] += x;
        __syncthreads();
    }
    if (t < SCAN_NB) bsums[t] = s[t] - v;
}

__global__ __launch_bounds__(SCAN_BS) void add_offsets(int* __restrict__ offs,
                                                       const int* __restrict__ bsums,
                                                       int* __restrict__ cursor) {
    int i = blockIdx.x * SCAN_BS + threadIdx.x;
    int o = offs[i] + bsums[blockIdx.x];
    offs[i] = o;
    if (i < NN) cursor[i] = o;
}

// ---------------------------------------------------------------------------
// Scatter into combined incidence CSR; ONE 4-byte store per entry:
// adj[p] = (round(q*32768) << 17) | other   (q<1, other<2^17)
// ---------------------------------------------------------------------------
__global__ __launch_bounds__(256) void scatter_kernel(
    const int* __restrict__ esrc, const int* __restrict__ edst,
    const float* __restrict__ ew, const unsigned long long* __restrict__ pk,
    int* __restrict__ cursor, unsigned int* __restrict__ adj) {
    int i = blockIdx.x * 256 + threadIdx.x;
    if (i < EE) {
        int s = esrc[i], d = edst[i];
        int deg = (int)(pk[s] >> 32);
        float q = ew[i] / (float)deg;
        unsigned q15 = (unsigned)(q * 32768.f + 0.5f);
        if (q15 > 32767u) q15 = 32767u;
        unsigned hi = q15 << 17;
        int p1 = atomicAdd(&cursor[s], 1);
        adj[p1] = hi | (unsigned)d;
        int p2 = atomicAdd(&cursor[d], 1);
        adj[p2] = hi | (unsigned)s;
    }
}

// ---------------------------------------------------------------------------
// Gather transport: one wave per node, lane = bin; unroll-4 for MLP.
// ---------------------------------------------------------------------------
__global__ __launch_bounds__(256) void gather_kernel(
    const unsigned short* __restrict__ fb16, const int* __restrict__ offs,
    const unsigned int* __restrict__ adj, const float* __restrict__ xi,
    float* __restrict__ trans) {
    const float QS = 1.f / 32768.f;
    int lane = threadIdx.x & 63;
    int n = blockIdx.x * 4 + (threadIdx.x >> 6);
    if (n >= NN) return;
    int j = offs[n];
    int end = offs[n + 1];
    float a0 = 0.f, a1 = 0.f, a2 = 0.f, a3 = 0.f, qs = 0.f;
    for (; j + 4 <= end; j += 4) {
        unsigned v0 = adj[j], v1 = adj[j + 1], v2 = adj[j + 2], v3 = adj[j + 3];
        float f0 = bf2f(fb16[(v0 & 0x1FFFFu) * 64 + lane]);
        float f1 = bf2f(fb16[(v1 & 0x1FFFFu) * 64 + lane]);
        float f2 = bf2f(fb16[(v2 & 0x1FFFFu) * 64 + lane]);
        float f3 = bf2f(fb16[(v3 & 0x1FFFFu) * 64 + lane]);
        float q0 = (float)(v0 >> 17) * QS;
        float q1 = (float)(v1 >> 17) * QS;
        float q2 = (float)(v2 >> 17) * QS;
        float q3 = (float)(v3 >> 17) * QS;
        a0 = fmaf(q0, f0, a0);
        a1 = fmaf(q1, f1, a1);
        a2 = fmaf(q2, f2, a2);
        a3 = fmaf(q3, f3, a3);
        qs += (q0 + q1) + (q2 + q3);
    }
    for (; j < end; j++) {
        unsigned v0 = adj[j];
        float q0 = (float)(v0 >> 17) * QS;
        a0 = fmaf(q0, bf2f(fb16[(v0 & 0x1FFFFu) * 64 + lane]), a0);
        qs += q0;
    }
    float acc = (a0 + a1) + (a2 + a3);
    float fn = bf2f(fb16[n * 64 + lane]);
    trans[n * 64 + lane] = xi[lane] * (acc - qs * fn);
}

// ---------------------------------------------------------------------------
// MFMA node kernel: 256 thr / 4 waves / 128 nodes per block.
// Wave w owns act rows [32w,32w+32): staging, MFMA A-reads and epilogue
// writes are all wave-private -> ZERO barriers in the layer loop.
// B-frags read directly from pre-transposed bf16 weights in global (L1-hit).
// ---------------------------------------------------------------------------
__global__ __launch_bounds__(256) void node_kernel(
    const unsigned short* __restrict__ fb16, const float* __restrict__ f,
    const float* __restrict__ macro_u, const float* __restrict__ source,
    const float* __restrict__ xi, const unsigned short* __restrict__ wp,
    const float* __restrict__ b_in, const float* __restrict__ b_hid,
    const float* __restrict__ b_out,
    const float* __restrict__ trans, float* __restrict__ out) {
    __shared__ __attribute__((aligned(16))) unsigned short act[128 * ACT_S];  // 18.4 KB
    __shared__ float s0s[128], s1s[128], us[128], xif[64];

    const int t = threadIdx.x;
    const int wid = t >> 6;
    const int lane = t & 63;
    const int m = lane & 15;
    const int quad = lane >> 4;
    const int nodeBase = blockIdx.x * 128;
    const int gbase = nodeBase * 64;

    if (t < 128) {
        int n = nodeBase + t;
        us[t] = (n < NN) ? macro_u[n] : 0.f;
    }
    if (t < 64) xif[t] = xi[t];

    // ---- wave-local staging: wave w stages its own rows [32w, 32w+32) ----
#pragma unroll
    for (int i = 0; i < 8; i++) {
        int r = wid * 32 + i * 4 + (lane >> 4);
        int c = (lane & 15) * 4;
        uint2 v = {0u, 0u};
        if (nodeBase + r < NN) v = *(const uint2*)&fb16[gbase + r * 64 + c];
        *(uint2*)&act[r * ACT_S + c] = v;
    }

    const int rowbase = wid * 32;

    for (int l = 0; l < 5; l++) {
        const unsigned short* W = wp + l * 4096;
        const float* B = (l == 0) ? b_in : (l < 4 ? b_hid + (l - 1) * 64 : b_out);

        short8 Af[2][2], Bf[4][2];
#pragma unroll
        for (int rt = 0; rt < 2; rt++)
#pragma unroll
            for (int kk = 0; kk < 2; kk++)
                Af[rt][kk] = *(const short8*)&act[(rowbase + rt * 16 + m) * ACT_S + kk * 32 + quad * 8];
#pragma unroll
        for (int ct = 0; ct < 4; ct++)
#pragma unroll
            for (int kk = 0; kk < 2; kk++)
                Bf[ct][kk] = *(const short8*)&W[(ct * 16 + m) * 64 + kk * 32 + quad * 8];

        f32x4 acc[2][4];
#pragma unroll
        for (int rt = 0; rt < 2; rt++)
#pragma unroll
            for (int ct = 0; ct < 4; ct++) {
                acc[rt][ct] = (f32x4){0.f, 0.f, 0.f, 0.f};
                acc[rt][ct] = __builtin_amdgcn_mfma_f32_16x16x32_bf16(Af[rt][0], Bf[ct][0], acc[rt][ct], 0, 0, 0);
                acc[rt][ct] = __builtin_amdgcn_mfma_f32_16x16x32_bf16(Af[rt][1], Bf[ct][1], acc[rt][ct], 0, 0, 0);
            }

#pragma unroll
        for (int rt = 0; rt < 2; rt++)
#pragma unroll
            for (int ct = 0; ct < 4; ct++) {
                float bv = B[ct * 16 + m];
#pragma unroll
                for (int r = 0; r < 4; r++) {
                    int row = rowbase + rt * 16 + quad * 4 + r;
                    float val = acc[rt][ct][r] + bv;
                    val = (l < 4) ? fmaxf(val, 0.f) : tanhf(val);
                    act[row * ACT_S + ct * 16 + m] = f2bf(val);
                }
            }
    }
    __syncthreads();   // all omega rows visible

    // ---- projection: analytic 2x2 Cramer per node ----
    if (t < 128) {
        float u = us[t];
        float v0 = 0.f, v1 = 0.f, sxs2 = 0.f, sxi = 0.f;
        const short8* rp = (const short8*)&act[t * ACT_S];
#pragma unroll
        for (int c = 0; c < 8; c++) {
            short8 v = rp[c];
#pragma unroll
            for (int jj = 0; jj < 8; jj++) {
                float om = bf2f((unsigned short)v[jj]);
                float xv = xif[c * 8 + jj];
                float xs = xv + u;
                v0 += om;
                v1 += xs * om;
                sxs2 += xs * xs;
                sxi += xv;
            }
        }
        v0 *= WQc;
        v1 *= WQc;
        float c00 = WQc + REGc;
        float c01 = WQc * WQc * (sxi + 64.f * u);
        float c11 = WQc * WQc * sxs2 + REGc;
        float det = c00 * c11 - c01 * c01;
        float inv = 1.0f / det;
        s0s[t] = (c11 * v0 - c01 * v1) * inv;
        s1s[t] = (c00 * v1 - c01 * v0) * inv;
    }
    __syncthreads();

    // ---- fused output sweep, 4 elems/thread (float4) ----
#pragma unroll
    for (int i = 0; i < 8; i++) {
        int e = (i * 256 + t) * 4;          // 0..8191, 4 elems same node row
        int nl = e >> 6;
        if (nodeBase + nl < NN) {
            int g = gbase + e;
            int c0 = e & 63;
            float4 fv = *(const float4*)&f[g];
            float4 sv = *(const float4*)&source[g];
            float4 tv = *(const float4*)&trans[g];
            float uu = us[nl];
            float sv0 = s0s[nl], sv1 = s1s[nl];
            float4 ov;
            float* ovp = (float*)&ov;
            const float* fp = (const float*)&fv;
            const float* sp = (const float*)&sv;
            const float* tp = (const float*)&tv;
#pragma unroll
            for (int jj = 0; jj < 4; jj++) {
                float om = bf2f(act[nl * ACT_S + c0 + jj]);
                float xs = xif[c0 + jj] + uu;
                float omst = om - WQc * (sv0 + xs * sv1);
                float val = fmaxf(fp[jj], 0.f) + DTc * (sp[jj] + omst - tp[jj]);
                ovp[jj] = fmaxf(val, 0.f);
            }
            *(float4*)&out[g] = ov;
        }
    }
}

extern "C" void kernel_launch(void* const* d_in, const int* in_sizes, int n_in,
                              void* d_out, int out_size, void* d_ws, size_t ws_size,
                              hipStream_t stream) {
    const float* f       = (const float*)d_in[0];
    const float* macro_u = (const float*)d_in[1];
    const float* source  = (const float*)d_in[2];
    const int*   esrc    = (const int*)d_in[3];
    const int*   edst    = (const int*)d_in[4];
    const float* ew      = (const float*)d_in[5];
    const float* xi      = (const float*)d_in[6];
    const float* w_in    = (const float*)d_in[7];
    const float* b_in    = (const float*)d_in[8];
    const float* w_hid   = (const float*)d_in[9];
    const float* b_hid   = (const float*)d_in[10];
    const float* w_out   = (const float*)d_in[11];
    const float* b_out   = (const float*)d_in[12];
    float* out = (float*)d_out;

    // workspace layout
    unsigned long long* pk = (unsigned long long*)d_ws;      // NN (8B)
    unsigned int* adj = (unsigned int*)(pk + NN);            // 2*EE (4B entries)
    int* offs   = (int*)(adj + 2 * EE);                      // SCAN_NB*SCAN_BS
    int* cursor = offs + SCAN_NB * SCAN_BS;                  // NN
    int* bsums  = cursor + NN;                               // 256
    float* trans = (float*)(bsums + 256);                    // NN*64
    unsigned short* fb16 = (unsigned short*)(trans + (size_t)NN * 64);  // NN*64
    unsigned short* wp = fb16 + (size_t)NN * 64;             // 5*4096

    hipMemsetAsync(pk, 0, (size_t)NN * sizeof(unsigned long long), stream);

    pre_kernel<<<(NN * 16 + 255) / 256, 256, 0, stream>>>(f, (unsigned int*)fb16);
    wprep_kernel<<<(5 * 4096 + 255) / 256, 256, 0, stream>>>(w_in, w_hid, w_out, wp);
    hist_kernel<<<(EE + 255) / 256, 256, 0, stream>>>(esrc, edst, pk);
    scan_blocks<<<SCAN_NB, SCAN_BS, 0, stream>>>(pk, offs, bsums);
    scan_sums<<<1, 256, 0, stream>>>(bsums);
    add_offsets<<<SCAN_NB, SCAN_BS, 0, stream>>>(offs, bsums, cursor);
    scatter_kernel<<<(EE + 255) / 256, 256, 0, stream>>>(esrc, edst, ew, pk, cursor, adj);
    gather_kernel<<<(NN + 3) / 4, 256, 0, stream>>>(fb16, offs, adj, xi, trans);
    node_kernel<<<(NN + 127) / 128, 256, 0, stream>>>(
        fb16, f, macro_u, source, xi, wp, b_in, b_hid, b_out, trans, out);
}